// Round 2
// baseline (643.540 us; speedup 1.0000x reference)
//
#include <hip/hip_runtime.h>
#include <math.h>

typedef unsigned short u16;
typedef __bf16 bf16;
typedef bf16 bf16x8 __attribute__((ext_vector_type(8)));
typedef float f32x4 __attribute__((ext_vector_type(4)));

#define DEV __device__ __forceinline__
#define FENCE() asm volatile("" ::: "memory")
#define LGKM0() asm volatile("s_waitcnt lgkmcnt(0)" ::: "memory")

DEV u16 f2b(float f) {
  unsigned u = __builtin_bit_cast(unsigned, f);
  u += 0x7fffu + ((u >> 16) & 1u);
  return (u16)(u >> 16);
}
DEV float b2f(u16 h) {
  unsigned u = ((unsigned)h) << 16;
  return __builtin_bit_cast(float, u);
}
DEV float gelu_f(float x) { return 0.5f * x * (1.0f + erff(x * 0.70710678118654752f)); }

DEV void gl2lds16(const void* g, void* l) {
  __builtin_amdgcn_global_load_lds(
      (const __attribute__((address_space(1))) unsigned int*)g,
      (__attribute__((address_space(3))) unsigned int*)l, 16, 0, 0);
}

// ---------------- weight transpose + fp32->bf16 ----------------
__global__ void k_transpose_cvt(const float* __restrict__ src, u16* __restrict__ dst,
                                int R, int C) {
  __shared__ float tile[32][33];
  const int c0 = blockIdx.x * 32, r0 = blockIdx.y * 32;
  const int tx = threadIdx.x, ty = threadIdx.y;  // 32 x 8
#pragma unroll
  for (int i = 0; i < 32; i += 8)
    tile[ty + i][tx] = src[(long)(r0 + ty + i) * C + c0 + tx];
  __syncthreads();
#pragma unroll
  for (int i = 0; i < 32; i += 8)
    dst[(long)(c0 + ty + i) * R + r0 + tx] = f2b(tile[tx][ty + i]);
}

// ---------------- FiLM ss = cond @ fw + fb, split-K ----------------
__global__ __launch_bounds__(256) void k_film_part(const float* __restrict__ cond,
                                                   const float* __restrict__ fw,
                                                   float* __restrict__ part) {
  const int j = blockIdx.x * 256 + threadIdx.x;  // 0..2047
  const int b = blockIdx.y;                      // 0..3
  const int kz = blockIdx.z;                     // 0..7
  const float* cp = cond + b * 1024 + kz * 128;
  const float* wp = fw + (long)kz * 128 * 2048 + j;
  float acc = 0.0f;
#pragma unroll 4
  for (int d = 0; d < 128; ++d) acc = fmaf(cp[d], wp[(long)d * 2048], acc);
  part[((kz * 4 + b) << 11) + j] = acc;
}
__global__ __launch_bounds__(256) void k_film_comb(const float* __restrict__ part,
                                                   const float* __restrict__ fb,
                                                   float* __restrict__ ss) {
  const int j = blockIdx.x * 256 + threadIdx.x;
  const int b = blockIdx.y;
  float a = fb[j];
#pragma unroll
  for (int kz = 0; kz < 8; ++kz) a += part[((kz * 4 + b) << 11) + j];
  ss[b * 2048 + j] = a;
}

// ---------------- fused RMSNorm + FiLM, fp32 in -> bf16 out ----------------
__global__ __launch_bounds__(256) void k_rmsfilm(const float* __restrict__ x,
                                                 const float* __restrict__ nw,
                                                 const float* __restrict__ ss,
                                                 u16* __restrict__ h) {
  const int row = blockIdx.x;  // 0..8191
  const int b = row >> 11;
  const int t = threadIdx.x;
  const float4 v = ((const float4*)(x + (long)row * 1024))[t];
  float s = v.x * v.x + v.y * v.y + v.z * v.z + v.w * v.w;
#pragma unroll
  for (int off = 32; off; off >>= 1) s += __shfl_xor(s, off);
  __shared__ float red[4];
  const int wv = t >> 6, lane = t & 63;
  if (lane == 0) red[wv] = s;
  __syncthreads();
  const float tot = red[0] + red[1] + red[2] + red[3];
  const float rn = rsqrtf(tot * (1.0f / 1024.0f) + 1e-6f);
  const float4 w4 = ((const float4*)nw)[t];
  const float4 sc = ((const float4*)(ss + b * 2048))[t];
  const float4 sh = ((const float4*)(ss + b * 2048 + 1024))[t];
  ushort4 o;
  o.x = f2b(v.x * rn * w4.x * (1.0f + sc.x) + sh.x);
  o.y = f2b(v.y * rn * w4.y * (1.0f + sc.y) + sh.y);
  o.z = f2b(v.z * rn * w4.z * (1.0f + sc.z) + sh.z);
  o.w = f2b(v.w * rn * w4.w * (1.0f + sc.w) + sh.w);
  ((ushort4*)(h + (long)row * 1024))[t] = o;
}

// ---------------- row softmax over 2048 bf16, in place ----------------
__global__ __launch_bounds__(256) void k_softmax(u16* __restrict__ S) {
  u16* p = S + ((long)blockIdx.x << 11);
  const int t = threadIdx.x;
  ushort4 u0 = ((ushort4*)p)[2 * t], u1 = ((ushort4*)p)[2 * t + 1];
  float f[8] = {b2f(u0.x), b2f(u0.y), b2f(u0.z), b2f(u0.w),
                b2f(u1.x), b2f(u1.y), b2f(u1.z), b2f(u1.w)};
  float m = f[0];
#pragma unroll
  for (int i = 1; i < 8; ++i) m = fmaxf(m, f[i]);
#pragma unroll
  for (int off = 32; off; off >>= 1) m = fmaxf(m, __shfl_xor(m, off));
  __shared__ float red[4];
  const int wv = t >> 6, lane = t & 63;
  if (lane == 0) red[wv] = m;
  __syncthreads();
  m = fmaxf(fmaxf(red[0], red[1]), fmaxf(red[2], red[3]));
  float s = 0.0f;
#pragma unroll
  for (int i = 0; i < 8; ++i) {
    f[i] = __expf(f[i] - m);
    s += f[i];
  }
#pragma unroll
  for (int off = 32; off; off >>= 1) s += __shfl_xor(s, off);
  __syncthreads();
  if (lane == 0) red[wv] = s;
  __syncthreads();
  const float inv = 1.0f / (red[0] + red[1] + red[2] + red[3]);
  ushort4 o0, o1;
  o0.x = f2b(f[0] * inv); o0.y = f2b(f[1] * inv);
  o0.z = f2b(f[2] * inv); o0.w = f2b(f[3] * inv);
  o1.x = f2b(f[4] * inv); o1.y = f2b(f[5] * inv);
  o1.z = f2b(f[6] * inv); o1.w = f2b(f[7] * inv);
  ((ushort4*)p)[2 * t] = o0;
  ((ushort4*)p)[2 * t + 1] = o1;
}

// ---------------- deep-pipelined bf16 MFMA GEMM ----------------
// C = A[M,K] @ Bt[N,K]^T, BK=32, DEPTH=4 LDS buffers, counted vmcnt (never
// drains in steady state), raw s_barrier (no implicit vmcnt(0) drain).
enum { EB = 1, ES = 2, EG = 4, ER = 8, EQKV = 16 };

template <int BM, int BN, int WM, int WN, int EPI, typename OutT>
__global__ __launch_bounds__(512, 1) void k_gemm(
    const u16* __restrict__ A, const u16* __restrict__ B, OutT* __restrict__ C,
    const float* __restrict__ bias, const float* __restrict__ bias2,
    const float* __restrict__ bias3, const float* __restrict__ resid,
    u16* __restrict__ Vt, float scale, int N, int K, long sAb, long sBb, long sCb) {
  constexpr int WROWS = BM / WM;  // rows per wave (128 or 64)
  constexpr int MR = WROWS / 16;  // m-frags per wave (8 or 4)
  constexpr int NAJ = BM / 128;   // A stage issues/thread (2)
  constexpr int NBJ = BN / 128;   // B stage issues/thread (2 or 1)
  constexpr int PI = NAJ + NBJ;   // vmem instr per tile per wave (4 or 3)
  __shared__ u16 As[4 * BM * 32];
  __shared__ u16 Bs[4 * BN * 32];

  const int tid = threadIdx.x, lane = tid & 63, wid = tid >> 6;
  const int wm = wid / WN, wn = wid % WN;
  const int r = lane & 15, q = lane >> 4;

  // XCD-aware swizzle (all launches have gridDim.x*gridDim.y % 8 == 0)
  int flat = blockIdx.y * gridDim.x + blockIdx.x;
  const int nxy = gridDim.x * gridDim.y;
  flat = (flat & 7) * (nxy >> 3) + (flat >> 3);
  const int bx = flat % gridDim.x, by = flat / gridDim.x;

  const long bm = (long)by * BM, bn = (long)bx * BN;
  const u16* Ab = A + (long)blockIdx.z * sAb + bm * K;
  const u16* Bb = B + (long)blockIdx.z * sBb + bn * K;

  const int arow = tid >> 2, aslot = tid & 3;
  const int ldsb = (tid & ~63) * 8;  // wave-uniform chunk base (elements)

  f32x4 acc[MR][4] = {};
  const int NT = K >> 5;

  auto stageA = [&](int buf, int k0) {
#pragma unroll
    for (int j = 0; j < NAJ; ++j)
      gl2lds16(Ab + (long)(j * 128 + arow) * K + k0 + aslot * 8,
               As + buf * (BM * 32) + j * 4096 + ldsb);
  };
  auto stageB = [&](int buf, int k0) {
#pragma unroll
    for (int j = 0; j < NBJ; ++j)
      gl2lds16(Bb + (long)(j * 128 + arow) * K + k0 + aslot * 8,
               Bs + buf * (BN * 32) + j * 4096 + ldsb);
  };

  // prologue: stage tiles 0..2 into bufs 0..2; wait until tile 0 landed
#pragma unroll
  for (int t = 0; t < 3; ++t) { stageA(t, t * 32); stageB(t, t * 32); }
  if constexpr (PI == 4) asm volatile("s_waitcnt vmcnt(8)" ::: "memory");
  else                   asm volatile("s_waitcnt vmcnt(6)" ::: "memory");
  __builtin_amdgcn_s_barrier();
  FENCE();

  for (int t = 0; t < NT; ++t) {
    const int buf = t & 3;
    const u16* Abuf = As + buf * (BM * 32);
    const u16* Bbuf = Bs + buf * (BN * 32);
    const int pbuf = (t + 3) & 3;
    const int pk = (t + 3) * 32;
    const bool pf = (t + 3) < NT;

    bf16x8 aa[4], bb[4];
#pragma unroll
    for (int ni = 0; ni < 4; ++ni)
      bb[ni] = *(const bf16x8*)&Bbuf[(wn * 64 + ni * 16 + r) * 32 + q * 8];
#pragma unroll
    for (int mi = 0; mi < 4; ++mi)
      aa[mi] = *(const bf16x8*)&Abuf[(wm * WROWS + mi * 16 + r) * 32 + q * 8];
    if (pf) stageA(pbuf, pk);
    if constexpr (MR == 4) { if (pf) stageB(pbuf, pk); }
    FENCE();
    __builtin_amdgcn_s_barrier();
    LGKM0();
    __builtin_amdgcn_sched_barrier(0);
    __builtin_amdgcn_s_setprio(1);
#pragma unroll
    for (int mi = 0; mi < 4; ++mi)
#pragma unroll
      for (int ni = 0; ni < 4; ++ni)
        acc[mi][ni] = __builtin_amdgcn_mfma_f32_16x16x32_bf16(aa[mi], bb[ni], acc[mi][ni], 0, 0, 0);
    __builtin_amdgcn_s_setprio(0);

    if constexpr (MR == 8) {
      FENCE();
      __builtin_amdgcn_s_barrier();  // end phase 0
#pragma unroll
      for (int mi = 0; mi < 4; ++mi)
        aa[mi] = *(const bf16x8*)&Abuf[(wm * WROWS + (mi + 4) * 16 + r) * 32 + q * 8];
      if (pf) stageB(pbuf, pk);
      FENCE();
      __builtin_amdgcn_s_barrier();
      LGKM0();
      __builtin_amdgcn_sched_barrier(0);
      __builtin_amdgcn_s_setprio(1);
#pragma unroll
      for (int mi = 0; mi < 4; ++mi)
#pragma unroll
        for (int ni = 0; ni < 4; ++ni)
          acc[mi + 4][ni] = __builtin_amdgcn_mfma_f32_16x16x32_bf16(aa[mi], bb[ni], acc[mi + 4][ni], 0, 0, 0);
      __builtin_amdgcn_s_setprio(0);
    }
    FENCE();
    // counted end-of-tile wait: ensure tile t+1 fully landed; keep rest in flight
    if (t + 3 < NT) {
      if constexpr (PI == 4) asm volatile("s_waitcnt vmcnt(8)" ::: "memory");
      else                   asm volatile("s_waitcnt vmcnt(6)" ::: "memory");
    } else if (t + 2 < NT) {
      if constexpr (PI == 4) asm volatile("s_waitcnt vmcnt(4)" ::: "memory");
      else                   asm volatile("s_waitcnt vmcnt(3)" ::: "memory");
    } else if (t + 1 < NT) {
      asm volatile("s_waitcnt vmcnt(0)" ::: "memory");
    }
    __builtin_amdgcn_s_barrier();
    FENCE();
  }

  // ---------------- epilogue ----------------
  const long cb = (long)blockIdx.z * sCb;
#pragma unroll
  for (int ni = 0; ni < 4; ++ni) {
    const long col = bn + wn * 64 + ni * 16 + r;
    float bv = 0.0f;
    int reg = 0, c = (int)col;
    if constexpr ((EPI & EB) != 0) bv = bias[col];
    if constexpr ((EPI & EQKV) != 0) {
      reg = (int)(col >> 10);
      c = (int)col & 1023;
      bv = (reg == 0) ? bias[c] : (reg == 1) ? bias2[c] : bias3[c];
    }
#pragma unroll
    for (int mi = 0; mi < MR; ++mi) {
#pragma unroll
      for (int j = 0; j < 4; ++j) {
        const long row = bm + wm * WROWS + mi * 16 + q * 4 + j;
        float v = acc[mi][ni][j];
        if constexpr ((EPI & ES) != 0) v *= scale;
        if constexpr ((EPI & (EB | EQKV)) != 0) v += bv;
        if constexpr ((EPI & EG) != 0) v = gelu_f(v);
        if constexpr ((EPI & ER) != 0) v += resid[row * N + col];
        if constexpr ((EPI & EQKV) != 0) {
          if (reg < 2)
            ((u16*)C)[(long)reg * 8388608 + row * 1024 + c] = f2b(v);
          else
            Vt[((row >> 11) << 21) + ((long)c << 11) + (row & 2047)] = f2b(v);
        } else if constexpr (sizeof(OutT) == 4) {
          C[cb + row * N + col] = v;
        } else {
          C[cb + row * N + col] = f2b(v);
        }
      }
    }
  }
}

extern "C" void kernel_launch(void* const* d_in, const int* in_sizes, int n_in,
                              void* d_out, int out_size, void* d_ws, size_t ws_size,
                              hipStream_t stream) {
  const float* x    = (const float*)d_in[0];
  const float* cond = (const float*)d_in[1];
  const float* n1w  = (const float*)d_in[2];
  const float* f1w  = (const float*)d_in[3];
  const float* f1b  = (const float*)d_in[4];
  const float* qw   = (const float*)d_in[5];
  const float* qb   = (const float*)d_in[6];
  const float* kw   = (const float*)d_in[7];
  const float* kb   = (const float*)d_in[8];
  const float* vw   = (const float*)d_in[9];
  const float* vb   = (const float*)d_in[10];
  const float* pw   = (const float*)d_in[11];
  const float* pb   = (const float*)d_in[12];
  const float* n2w  = (const float*)d_in[13];
  const float* f2w  = (const float*)d_in[14];
  const float* f2b_ = (const float*)d_in[15];
  const float* w1   = (const float*)d_in[16];
  const float* b1   = (const float*)d_in[17];
  const float* w2   = (const float*)d_in[18];
  const float* b2   = (const float*)d_in[19];
  float* out = (float*)d_out;

  char* ws = (char*)d_ws;
  size_t o = 0;
  auto alloc = [&](size_t bytes) {
    size_t ret = o;
    o += (bytes + 255) & ~(size_t)255;
    return ret;
  };
  const long N = 2048, D = 1024, H = 4096;

  u16* qkvT = (u16*)(ws + alloc(3 * D * D * 2));  // [3072][1024] = qT;kT;vT
  u16* pT   = (u16*)(ws + alloc(D * D * 2));
  u16* w1T  = (u16*)(ws + alloc(D * H * 2));
  u16* w2T  = (u16*)(ws + alloc(D * H * 2));
  float* ss1  = (float*)(ws + alloc(4 * 2 * D * 4));
  float* ss2  = (float*)(ws + alloc(4 * 2 * D * 4));
  float* part = (float*)(ws + alloc(8 * 4 * 2 * D * 4));
  u16* h    = (u16*)(ws + alloc(4 * N * D * 2));    // 16 MB
  float* x1 = (float*)(ws + alloc(4 * N * D * 4));  // 32 MB
  u16* AO   = (u16*)(ws + alloc(4 * N * D * 2));    // 16 MB
  const size_t big = o;  // alias region
  u16* Q    = (u16*)(ws + alloc(4 * N * D * 2));    // Q and Kb must stay adjacent
  u16* Kb   = (u16*)(ws + alloc(4 * N * D * 2));
  u16* Vt   = (u16*)(ws + alloc(4 * N * D * 2));
  u16* S    = (u16*)(ws + alloc(4 * N * N * 2));    // 32 MB
  u16* h1   = (u16*)(ws + big);                     // 64 MB, aliases Q..S
  (void)ws_size; (void)in_sizes; (void)n_in; (void)out_size; (void)Kb;

  dim3 tb(32, 8);
  k_transpose_cvt<<<dim3(32, 32), tb, 0, stream>>>(qw, qkvT, 1024, 1024);
  k_transpose_cvt<<<dim3(32, 32), tb, 0, stream>>>(kw, qkvT + 1024 * 1024, 1024, 1024);
  k_transpose_cvt<<<dim3(32, 32), tb, 0, stream>>>(vw, qkvT + 2 * 1024 * 1024, 1024, 1024);
  k_transpose_cvt<<<dim3(32, 32), tb, 0, stream>>>(pw, pT, 1024, 1024);
  k_transpose_cvt<<<dim3(128, 32), tb, 0, stream>>>(w1, w1T, 1024, 4096);
  k_transpose_cvt<<<dim3(32, 128), tb, 0, stream>>>(w2, w2T, 4096, 1024);

  k_film_part<<<dim3(8, 4, 8), 256, 0, stream>>>(cond, f1w, part);
  k_film_comb<<<dim3(8, 4), 256, 0, stream>>>(part, f1b, ss1);
  k_film_part<<<dim3(8, 4, 8), 256, 0, stream>>>(cond, f2w, part);
  k_film_comb<<<dim3(8, 4), 256, 0, stream>>>(part, f2b_, ss2);

  k_rmsfilm<<<8192, 256, 0, stream>>>(x, n1w, ss1, h);

  // fused QKV: [8192,1024] @ [3072,1024]^T ; V stored transposed per batch
  k_gemm<256, 256, 2, 4, EQKV, u16><<<dim3(12, 32, 1), 512, 0, stream>>>(
      h, qkvT, Q, qb, kb, vb, nullptr, Vt, 1.0f, 3072, 1024, 0, 0, 0);

  // S = Q @ K^T * D^-0.5 (batched)
  k_gemm<256, 256, 2, 4, ES, u16><<<dim3(8, 8, 4), 512, 0, stream>>>(
      Q, Kb, S, nullptr, nullptr, nullptr, nullptr, nullptr, 0.03125f,
      2048, 1024, N * D, N * D, N * N);
  k_softmax<<<8192, 256, 0, stream>>>(S);

  // AO = P @ V (batched; B-operand = Vt[d][n])
  k_gemm<256, 128, 4, 2, 0, u16><<<dim3(8, 8, 4), 512, 0, stream>>>(
      S, Vt, AO, nullptr, nullptr, nullptr, nullptr, nullptr, 1.0f,
      1024, 2048, N * N, D * N, N * D);

  // x1 = x + AO @ proj^T + pb
  k_gemm<256, 128, 4, 2, EB | ER, float><<<dim3(8, 32, 1), 512, 0, stream>>>(
      AO, pT, x1, pb, nullptr, nullptr, x, nullptr, 1.0f, 1024, 1024, 0, 0, 0);

  k_rmsfilm<<<8192, 256, 0, stream>>>(x1, n2w, ss2, h);

  // h1 = gelu(h @ w1 + b1)
  k_gemm<256, 256, 2, 4, EB | EG, u16><<<dim3(16, 32, 1), 512, 0, stream>>>(
      h, w1T, h1, b1, nullptr, nullptr, nullptr, nullptr, 1.0f, 4096, 1024, 0, 0, 0);

  // out = x1 + h1 @ w2 + b2
  k_gemm<256, 128, 4, 2, EB | ER, float><<<dim3(8, 32, 1), 512, 0, stream>>>(
      h1, w2T, out, b2, nullptr, nullptr, x1, nullptr, 1.0f, 1024, 4096, 0, 0, 0);
}